// Round 2
// baseline (515.771 us; speedup 1.0000x reference)
//
#include <hip/hip_runtime.h>
#include <math.h>

// Problem constants
#define B_   512
#define C_   24      // head dim of q / output channels
#define HW_  3136    // 56*56 queries per batch
#define M_   49      // kv tokens
#define D_   768     // z feature dim
#define DK_  24      // k/v head dim
#define ROWS (B_*M_)       // 25088 rows of z (b*49+m)
#define VOFF (ROWS*DK_)    // float offset of v block in workspace

#define KCHUNKS 4
#define KCH     (D_/KCHUNKS)   // 192
#define QBLK    13             // ceil(3136/256) query blocks per batch

// ---------------------------------------------------------------------------
// Kernel 0: init kv with biases (proj accumulates on top via atomicAdd).
// ---------------------------------------------------------------------------
__global__ __launch_bounds__(256) void init_kernel(
    const float* __restrict__ bk, const float* __restrict__ bv, float* __restrict__ kv)
{
    int i = blockIdx.x * 256 + threadIdx.x;
    if (i >= 2 * VOFF) return;
    int c = i % DK_;
    kv[i] = (i < VOFF) ? bk[c] : bv[c];
}

// ---------------------------------------------------------------------------
// Kernel 1: k/v projection, split-K.  Each block: 64 rows x 48 cols x 192 K.
// 128 threads, 4 rows x 6 cols per thread, LDS read via ds_read_b128:
//   zt row stride 36 floats (bank-staggered), W staged TRANSPOSED so each
//   column is a contiguous float4 run.  Epilogue: fp32 atomicAdd into kv.
// (unchanged — awaiting per-dispatch counters before touching)
// ---------------------------------------------------------------------------
__global__ __launch_bounds__(128, 6) void proj_kernel(
    const float* __restrict__ z, const float* __restrict__ Wk,
    const float* __restrict__ Wv, float* __restrict__ kv)
{
    __shared__ float zt[64][36];   // stride 36: rows land on staggered banks
    __shared__ float wt[48][36];   // wt[c][kk]  (transposed W chunk)

    const int t     = threadIdx.x;
    const int tile  = blockIdx.x >> 2;          // 392 row tiles
    const int chunk = blockIdx.x & 3;           // 4 K-chunks of 192
    const int r0    = tile * 64;
    const int rb    = t & 15;                   // rows rb + {0,16,32,48}
    const int c0    = (t >> 4) * 6;             // cols c0..c0+5, never straddles 24

    float acc[4][6];
    #pragma unroll
    for (int i = 0; i < 4; ++i)
        #pragma unroll
        for (int j = 0; j < 6; ++j) acc[i][j] = 0.f;

    for (int s = 0; s < KCH; s += 32) {
        const int kc = chunk * KCH + s;
        // stage z tile 64x32 (float4/thread x4, coalesced)
        #pragma unroll
        for (int p = 0; p < 4; ++p) {
            int lin = p * 128 + t;
            int row = lin >> 3;
            int col = (lin & 7) * 4;
            const float4 zv = *(const float4*)(z + (size_t)(r0 + row) * D_ + kc + col);
            *(float4*)&zt[row][col] = zv;
        }
        // stage W chunk 32x48 transposed into wt[c][d]  (6 KB, L2-hot)
        #pragma unroll
        for (int i = 0; i < 12; ++i) {
            int idx = i * 128 + t;              // 0..1535
            int d = idx & 31;
            int c = idx >> 5;                   // 0..47
            wt[c][d] = (c < 24) ? Wk[(kc + d) * DK_ + c] : Wv[(kc + d) * DK_ + (c - 24)];
        }
        __syncthreads();
        #pragma unroll
        for (int k4 = 0; k4 < 8; ++k4) {
            float4 za[4], wa[6];
            #pragma unroll
            for (int i = 0; i < 4; ++i) za[i] = *(const float4*)&zt[rb + 16 * i][k4 * 4];
            #pragma unroll
            for (int j = 0; j < 6; ++j) wa[j] = *(const float4*)&wt[c0 + j][k4 * 4];
            #pragma unroll
            for (int i = 0; i < 4; ++i)
                #pragma unroll
                for (int j = 0; j < 6; ++j) {
                    acc[i][j] += za[i].x * wa[j].x;
                    acc[i][j] += za[i].y * wa[j].y;
                    acc[i][j] += za[i].z * wa[j].z;
                    acc[i][j] += za[i].w * wa[j].w;
                }
        }
        __syncthreads();
    }

    // epilogue: atomic accumulate into k or v block
    #pragma unroll
    for (int j = 0; j < 6; ++j) {
        int c = c0 + j;
        float* base = (c < 24) ? kv : (kv + VOFF);
        int cc = (c < 24) ? c : (c - 24);
        #pragma unroll
        for (int i = 0; i < 4; ++i) {
            int rg = r0 + rb + 16 * i;
            atomicAdd(&base[(size_t)rg * DK_ + cc], acc[i][j]);
        }
    }
}

// ---------------------------------------------------------------------------
// Kernel 2: attention + residual.  256-thread blocks, one thread per query,
// streaming MAX-FREE softmax (dots std ~0.58, exp fp32-safe).
//
// SPILL-FIX (round 0, carried):
//   - __launch_bounds__(256, 6): 85-VGPR cap fits the ~60-70 live set
//     (q[24]+o[24]+addr+temps); the old (256,8)=64-cap likely spilled.
//     Still 24 waves/CU of TLP for SMEM latency hiding.
//   - unroll 1 on the m-loop: one k/v row (48 uniform scalars) in flight;
//     unroll 7 wanted 336 scalars -> SGPR spill pressure.
// ROUND-1 MICRO: fold 24^-0.5 into q at load; hot loop loses a*scale mult.
// ---------------------------------------------------------------------------
__global__ __launch_bounds__(256, 6) void attn_kernel(
    const float* __restrict__ x, const float* __restrict__ kv, float* __restrict__ out)
{
    const int b  = blockIdx.x / QBLK;
    const int hw = (blockIdx.x % QBLK) * 256 + threadIdx.x;
    if (hw >= HW_) return;

    const float scale = 0.20412414523193154f;               // 24^-0.5

    const float* xb = x + (size_t)b * (C_ * HW_);
    float q[C_];
    #pragma unroll
    for (int c = 0; c < C_; ++c) q[c] = xb[c * HW_ + hw] * scale;   // coalesced

    const float* kb = kv + (size_t)b * (M_ * DK_);
    const float* vb = kv + VOFF + (size_t)b * (M_ * DK_);

    float o[C_];
    #pragma unroll
    for (int c = 0; c < C_; ++c) o[c] = 0.f;
    float s = 0.f;

    #pragma unroll 1
    for (int m = 0; m < M_; ++m) {
        float a = 0.f;
        #pragma unroll
        for (int c = 0; c < DK_; ++c) a += q[c] * kb[m * DK_ + c];
        float p = __expf(a);
        s += p;
        #pragma unroll
        for (int c = 0; c < C_; ++c) o[c] += p * vb[m * DK_ + c];
    }
    const float inv = 1.f / s;

    // flat-view residual: thread q owns flat [q*24, q*24+24)
    const float* xr = xb + (size_t)hw * C_;
    float*       ob = out + (size_t)b * (C_ * HW_) + (size_t)hw * C_;
    #pragma unroll
    for (int c4 = 0; c4 < C_; c4 += 4) {
        float4 xv = *(const float4*)(xr + c4);
        float4 ov;
        ov.x = xv.x + o[c4+0] * inv;
        ov.y = xv.y + o[c4+1] * inv;
        ov.z = xv.z + o[c4+2] * inv;
        ov.w = xv.w + o[c4+3] * inv;
        *(float4*)(ob + c4) = ov;
    }
}

// ---------------------------------------------------------------------------
extern "C" void kernel_launch(void* const* d_in, const int* in_sizes, int n_in,
                              void* d_out, int out_size, void* d_ws, size_t ws_size,
                              hipStream_t stream) {
    const float* x  = (const float*)d_in[0];
    const float* z  = (const float*)d_in[1];
    const float* Wk = (const float*)d_in[2];
    const float* bk = (const float*)d_in[3];
    const float* Wv = (const float*)d_in[4];
    const float* bv = (const float*)d_in[5];
    float* out = (float*)d_out;
    float* kv  = (float*)d_ws;   // 2*25088*24*4 = 4.8 MB

    init_kernel<<<(2 * VOFF + 255) / 256, 256, 0, stream>>>(bk, bv, kv);
    proj_kernel<<<(ROWS / 64) * KCHUNKS, 128, 0, stream>>>(z, Wk, Wv, kv);
    attn_kernel<<<B_ * QBLK, 256, 0, stream>>>(x, kv, out);
}

// Round 3
// 450.513 us; speedup vs baseline: 1.1449x; 1.1449x over previous
//
#include <hip/hip_runtime.h>
#include <math.h>

// Problem constants
#define B_   512
#define C_   24      // head dim of q / output channels
#define HW_  3136    // 56*56 queries per batch
#define M_   49      // kv tokens
#define D_   768     // z feature dim
#define DK_  24      // k/v head dim
#define ROWS (B_*M_)       // 25088 rows of z (b*49+m)
#define VOFF (ROWS*DK_)    // float offset of v block in kv workspace

#define KCHUNKS 8
#define KCH     (D_/KCHUNKS)   // 96
#define QBLK    13             // ceil(3136/256) query blocks per batch
#define PCOLS   48
#define PSTRIDE ((size_t)ROWS * PCOLS)   // floats per chunk-partial (1,204,224)

// ---------------------------------------------------------------------------
// Kernel 1: k/v projection, split-K=8, ATOMIC-FREE.
// Each block: 64 rows x 48 cols x 96 K.  128 threads, 4 rows x 6 cols per
// thread.  Epilogue: plain float2 stores of partials into scratch (d_out).
// ROUND-2 CHANGE (atomic-amplification theory):
//   - old epilogue: 4.8M device-scope fp32 atomicAdds -> WRITE_SIZE 112.9 MB
//     (23x amplification), VALUBusy 14%, dur 166 us.  Replaced with plain
//     partial stores + reduce kernel.
//   - KCHUNKS 4->8: grid 1568->3136 blocks, occupancy ceiling 38%->77%.
// ---------------------------------------------------------------------------
__global__ __launch_bounds__(128, 6) void proj_kernel(
    const float* __restrict__ z, const float* __restrict__ Wk,
    const float* __restrict__ Wv, float* __restrict__ part)
{
    __shared__ float zt[64][36];   // stride 36: rows land on staggered banks
    __shared__ float wt[48][36];   // wt[c][kk]  (transposed W chunk)

    const int t     = threadIdx.x;
    const int tile  = blockIdx.x >> 3;          // 392 row tiles
    const int chunk = blockIdx.x & 7;           // 8 K-chunks of 96
    const int r0    = tile * 64;
    const int rb    = t & 15;                   // rows rb + {0,16,32,48}
    const int c0    = (t >> 4) * 6;             // cols c0..c0+5, never straddles 24

    float acc[4][6];
    #pragma unroll
    for (int i = 0; i < 4; ++i)
        #pragma unroll
        for (int j = 0; j < 6; ++j) acc[i][j] = 0.f;

    for (int s = 0; s < KCH; s += 32) {
        const int kc = chunk * KCH + s;
        // stage z tile 64x32 (float4/thread x4, coalesced)
        #pragma unroll
        for (int p = 0; p < 4; ++p) {
            int lin = p * 128 + t;
            int row = lin >> 3;
            int col = (lin & 7) * 4;
            const float4 zv = *(const float4*)(z + (size_t)(r0 + row) * D_ + kc + col);
            *(float4*)&zt[row][col] = zv;
        }
        // stage W chunk 32x48 transposed into wt[c][d]  (6 KB, L2-hot)
        #pragma unroll
        for (int i = 0; i < 12; ++i) {
            int idx = i * 128 + t;              // 0..1535
            int d = idx & 31;
            int c = idx >> 5;                   // 0..47
            wt[c][d] = (c < 24) ? Wk[(kc + d) * DK_ + c] : Wv[(kc + d) * DK_ + (c - 24)];
        }
        __syncthreads();
        #pragma unroll
        for (int k4 = 0; k4 < 8; ++k4) {
            float4 za[4], wa[6];
            #pragma unroll
            for (int i = 0; i < 4; ++i) za[i] = *(const float4*)&zt[rb + 16 * i][k4 * 4];
            #pragma unroll
            for (int j = 0; j < 6; ++j) wa[j] = *(const float4*)&wt[c0 + j][k4 * 4];
            #pragma unroll
            for (int i = 0; i < 4; ++i)
                #pragma unroll
                for (int j = 0; j < 6; ++j) {
                    acc[i][j] += za[i].x * wa[j].x;
                    acc[i][j] += za[i].y * wa[j].y;
                    acc[i][j] += za[i].z * wa[j].z;
                    acc[i][j] += za[i].w * wa[j].w;
                }
        }
        __syncthreads();
    }

    // epilogue: plain partial stores (float2: c0 even -> 8B aligned)
    #pragma unroll
    for (int i = 0; i < 4; ++i) {
        float* base = part + (size_t)chunk * PSTRIDE
                           + (size_t)(r0 + rb + 16 * i) * PCOLS + c0;
        #pragma unroll
        for (int j = 0; j < 6; j += 2) {
            float2 v2 = make_float2(acc[i][j], acc[i][j + 1]);
            *(float2*)(base + j) = v2;
        }
    }
}

// ---------------------------------------------------------------------------
// Kernel 1b: reduce partials + biases into kv (absorbs old init_kernel).
// 1,204,224 outputs; one thread each; fully coalesced reads/writes.
// Traffic: 38.5 MB read + 4.8 MB write  ->  ~8 us HBM-bound.
// ---------------------------------------------------------------------------
__global__ __launch_bounds__(256) void reduce_kernel(
    const float* __restrict__ part, const float* __restrict__ bk,
    const float* __restrict__ bv, float* __restrict__ kv)
{
    int i = blockIdx.x * 256 + threadIdx.x;     // i in [0, ROWS*48)
    int row = i / PCOLS;
    int c   = i - row * PCOLS;

    float v = 0.f;
    #pragma unroll
    for (int k = 0; k < KCHUNKS; ++k) v += part[(size_t)k * PSTRIDE + i];

    if (c < DK_) kv[(size_t)row * DK_ + c]               = v + bk[c];
    else         kv[VOFF + (size_t)row * DK_ + (c - DK_)] = v + bv[c - DK_];
}

// ---------------------------------------------------------------------------
// Kernel 2: attention + residual.  256-thread blocks, one thread per query,
// streaming MAX-FREE softmax (dots std ~0.58, exp fp32-safe).
// (unchanged this round — spill-fix (256,6)+unroll-1 and folded scale kept;
//  its counters become visible now that proj drops out of the top-5)
// ---------------------------------------------------------------------------
__global__ __launch_bounds__(256, 6) void attn_kernel(
    const float* __restrict__ x, const float* __restrict__ kv, float* __restrict__ out)
{
    const int b  = blockIdx.x / QBLK;
    const int hw = (blockIdx.x % QBLK) * 256 + threadIdx.x;
    if (hw >= HW_) return;

    const float scale = 0.20412414523193154f;               // 24^-0.5

    const float* xb = x + (size_t)b * (C_ * HW_);
    float q[C_];
    #pragma unroll
    for (int c = 0; c < C_; ++c) q[c] = xb[c * HW_ + hw] * scale;   // coalesced

    const float* kb = kv + (size_t)b * (M_ * DK_);
    const float* vb = kv + VOFF + (size_t)b * (M_ * DK_);

    float o[C_];
    #pragma unroll
    for (int c = 0; c < C_; ++c) o[c] = 0.f;
    float s = 0.f;

    #pragma unroll 1
    for (int m = 0; m < M_; ++m) {
        float a = 0.f;
        #pragma unroll
        for (int c = 0; c < DK_; ++c) a += q[c] * kb[m * DK_ + c];
        float p = __expf(a);
        s += p;
        #pragma unroll
        for (int c = 0; c < C_; ++c) o[c] += p * vb[m * DK_ + c];
    }
    const float inv = 1.f / s;

    // flat-view residual: thread q owns flat [q*24, q*24+24)
    const float* xr = xb + (size_t)hw * C_;
    float*       ob = out + (size_t)b * (C_ * HW_) + (size_t)hw * C_;
    #pragma unroll
    for (int c4 = 0; c4 < C_; c4 += 4) {
        float4 xv = *(const float4*)(xr + c4);
        float4 ov;
        ov.x = xv.x + o[c4+0] * inv;
        ov.y = xv.y + o[c4+1] * inv;
        ov.z = xv.z + o[c4+2] * inv;
        ov.w = xv.w + o[c4+3] * inv;
        *(float4*)(ob + c4) = ov;
    }
}

// ---------------------------------------------------------------------------
// Launch:  proj partials land in d_out used as scratch (38.5 MB << 154 MB;
// attn fully overwrites d_out afterwards, all stream-ordered).
// ---------------------------------------------------------------------------
extern "C" void kernel_launch(void* const* d_in, const int* in_sizes, int n_in,
                              void* d_out, int out_size, void* d_ws, size_t ws_size,
                              hipStream_t stream) {
    const float* x  = (const float*)d_in[0];
    const float* z  = (const float*)d_in[1];
    const float* Wk = (const float*)d_in[2];
    const float* bk = (const float*)d_in[3];
    const float* Wv = (const float*)d_in[4];
    const float* bv = (const float*)d_in[5];
    float* out  = (float*)d_out;
    float* part = (float*)d_out;   // scratch: KCHUNKS*ROWS*48*4 = 38.5 MB
    float* kv   = (float*)d_ws;    // 2*25088*24*4 = 4.8 MB

    proj_kernel<<<(ROWS / 64) * KCHUNKS, 128, 0, stream>>>(z, Wk, Wv, part);
    reduce_kernel<<<(ROWS * PCOLS) / 256, 256, 0, stream>>>(part, bk, bv, kv);
    attn_kernel<<<B_ * QBLK, 256, 0, stream>>>(x, kv, out);
}

// Round 4
// 445.794 us; speedup vs baseline: 1.1570x; 1.0106x over previous
//
#include <hip/hip_runtime.h>
#include <math.h>

// Problem constants
#define B_   512
#define C_   24      // head dim of q / output channels
#define HW_  3136    // 56*56 queries per batch
#define M_   49      // kv tokens
#define D_   768     // z feature dim
#define DK_  24      // k/v head dim
#define ROWS (B_*M_)       // 25088 rows of z (b*49+m)
#define VOFF (ROWS*DK_)    // float offset of v block in kv workspace

#define KCHUNKS 8
#define KCH     (D_/KCHUNKS)   // 96
#define QBLK    13             // ceil(3136/256) query blocks per batch
#define PCOLS   48
#define PSTRIDE ((size_t)ROWS * PCOLS)   // floats per chunk-partial (1,204,224)

// ---------------------------------------------------------------------------
// Kernel 1: k/v projection, split-K=8, atomic-free.
// ROUND-3: 256-thread blocks, 128-row tiles (was 128 thr / 64 rows).
//   - halves barrier count per output element, doubles staging parallelism.
//   - LDS 25.3 KB -> 6 blocks/CU ceiling = 24 waves/CU (grid gives 6.1
//     blocks/CU, so LDS is not the binding limit).
//   - per-thread shape unchanged: 4 rows x 6 cols, ds_read_b128 friendly.
// Epilogue: plain float2 partial stores (atomic-free, round-2 win: WRITE_SIZE
// was 112.9 MB with atomics -> 38.5 MB plain).
// ---------------------------------------------------------------------------
__global__ __launch_bounds__(256, 4) void proj_kernel(
    const float* __restrict__ z, const float* __restrict__ Wk,
    const float* __restrict__ Wv, float* __restrict__ part)
{
    __shared__ float zt[128][36];  // stride 36 floats = 144 B (16B-aligned rows)
    __shared__ float wt[48][36];   // wt[c][kk]  (transposed W chunk)

    const int t     = threadIdx.x;
    const int tile  = blockIdx.x >> 3;          // 196 row tiles
    const int chunk = blockIdx.x & 7;           // 8 K-chunks of 96
    const int r0    = tile * 128;
    const int rb    = t & 31;                   // rows rb + {0,32,64,96}
    const int c0    = (t >> 5) * 6;             // cols c0..c0+5, never straddles 24

    float acc[4][6];
    #pragma unroll
    for (int i = 0; i < 4; ++i)
        #pragma unroll
        for (int j = 0; j < 6; ++j) acc[i][j] = 0.f;

    for (int s = 0; s < KCH; s += 32) {
        const int kc = chunk * KCH + s;
        // stage z tile 128x32 (float4/thread x4, coalesced 128B segments)
        #pragma unroll
        for (int p = 0; p < 4; ++p) {
            int lin = p * 256 + t;              // 0..1023
            int row = lin >> 3;
            int col = (lin & 7) * 4;
            const float4 zv = *(const float4*)(z + (size_t)(r0 + row) * D_ + kc + col);
            *(float4*)&zt[row][col] = zv;
        }
        // stage W chunk 32x48 transposed into wt[c][d]  (6 KB, L2-hot)
        #pragma unroll
        for (int i = 0; i < 6; ++i) {
            int idx = i * 256 + t;              // 0..1535
            int d = idx & 31;
            int c = idx >> 5;                   // 0..47
            wt[c][d] = (c < 24) ? Wk[(kc + d) * DK_ + c] : Wv[(kc + d) * DK_ + (c - 24)];
        }
        __syncthreads();
        #pragma unroll
        for (int k4 = 0; k4 < 8; ++k4) {
            float4 za[4], wa[6];
            #pragma unroll
            for (int i = 0; i < 4; ++i) za[i] = *(const float4*)&zt[rb + 32 * i][k4 * 4];
            #pragma unroll
            for (int j = 0; j < 6; ++j) wa[j] = *(const float4*)&wt[c0 + j][k4 * 4];
            #pragma unroll
            for (int i = 0; i < 4; ++i)
                #pragma unroll
                for (int j = 0; j < 6; ++j) {
                    acc[i][j] += za[i].x * wa[j].x;
                    acc[i][j] += za[i].y * wa[j].y;
                    acc[i][j] += za[i].z * wa[j].z;
                    acc[i][j] += za[i].w * wa[j].w;
                }
        }
        __syncthreads();
    }

    // epilogue: plain partial stores (float2: c0 even -> 8B aligned)
    #pragma unroll
    for (int i = 0; i < 4; ++i) {
        float* base = part + (size_t)chunk * PSTRIDE
                           + (size_t)(r0 + rb + 32 * i) * PCOLS + c0;
        #pragma unroll
        for (int j = 0; j < 6; j += 2) {
            float2 v2 = make_float2(acc[i][j], acc[i][j + 1]);
            *(float2*)(base + j) = v2;
        }
    }
}

// ---------------------------------------------------------------------------
// Kernel 1b: reduce partials + biases into kv (absorbs init).
// Traffic: 38.5 MB read + 4.8 MB write -> ~8 us HBM-bound.
// ---------------------------------------------------------------------------
__global__ __launch_bounds__(256) void reduce_kernel(
    const float* __restrict__ part, const float* __restrict__ bk,
    const float* __restrict__ bv, float* __restrict__ kv)
{
    int i = blockIdx.x * 256 + threadIdx.x;     // i in [0, ROWS*48)
    int row = i / PCOLS;
    int c   = i - row * PCOLS;

    float v = 0.f;
    #pragma unroll
    for (int k = 0; k < KCHUNKS; ++k) v += part[(size_t)k * PSTRIDE + i];

    if (c < DK_) kv[(size_t)row * DK_ + c]               = v + bk[c];
    else         kv[VOFF + (size_t)row * DK_ + (c - DK_)] = v + bv[c - DK_];
}

// ---------------------------------------------------------------------------
// Kernel 2: attention + residual.  One thread per query, streaming max-free
// softmax (dots std ~0.58, fp32-safe).  k/v rows are wave-uniform -> SGPR.
//
// ROUND-3 CHANGE (AGPR-shunt theory):
//   - VGPR_Count was 32 with a ~60-70 float live set -> compiler put q/o in
//     AGPRs, adding ~48 v_accvgpr moves per m-iter (measured VALU-issue
//     102 us vs 54 us of real FMA work = exactly 2x).  (256,6)->(256,4)
//     gives a 128-VGPR budget so q/o live in real VGPRs.  16 waves/CU TLP.
//   - 4-way split accumulators in the QK dot: dependency chain 24 FMA
//     (~96 cyc) -> 6 (~24 cyc); helps at the reduced occupancy.
//   - numerics untouched (absmax sits exactly at 0.015625).
// ---------------------------------------------------------------------------
__global__ __launch_bounds__(256, 4) void attn_kernel(
    const float* __restrict__ x, const float* __restrict__ kv, float* __restrict__ out)
{
    const int b  = blockIdx.x / QBLK;
    const int hw = (blockIdx.x % QBLK) * 256 + threadIdx.x;
    if (hw >= HW_) return;

    const float scale = 0.20412414523193154f;               // 24^-0.5

    const float* xb = x + (size_t)b * (C_ * HW_);
    float q[C_];
    #pragma unroll
    for (int c = 0; c < C_; ++c) q[c] = xb[c * HW_ + hw] * scale;   // coalesced

    const float* kb = kv + (size_t)b * (M_ * DK_);
    const float* vb = kv + VOFF + (size_t)b * (M_ * DK_);

    float o[C_];
    #pragma unroll
    for (int c = 0; c < C_; ++c) o[c] = 0.f;
    float s = 0.f;

    #pragma unroll 1
    for (int m = 0; m < M_; ++m) {
        float a0 = 0.f, a1 = 0.f, a2 = 0.f, a3 = 0.f;
        #pragma unroll
        for (int c = 0; c < DK_; c += 4) {
            a0 += q[c + 0] * kb[m * DK_ + c + 0];
            a1 += q[c + 1] * kb[m * DK_ + c + 1];
            a2 += q[c + 2] * kb[m * DK_ + c + 2];
            a3 += q[c + 3] * kb[m * DK_ + c + 3];
        }
        float p = __expf((a0 + a1) + (a2 + a3));
        s += p;
        #pragma unroll
        for (int c = 0; c < C_; ++c) o[c] += p * vb[m * DK_ + c];
    }
    const float inv = 1.f / s;

    // flat-view residual: thread q owns flat [q*24, q*24+24)
    const float* xr = xb + (size_t)hw * C_;
    float*       ob = out + (size_t)b * (C_ * HW_) + (size_t)hw * C_;
    #pragma unroll
    for (int c4 = 0; c4 < C_; c4 += 4) {
        float4 xv = *(const float4*)(xr + c4);
        float4 ov;
        ov.x = xv.x + o[c4+0] * inv;
        ov.y = xv.y + o[c4+1] * inv;
        ov.z = xv.z + o[c4+2] * inv;
        ov.w = xv.w + o[c4+3] * inv;
        *(float4*)(ob + c4) = ov;
    }
}

// ---------------------------------------------------------------------------
// Launch: proj partials land in d_out used as scratch (38.5 MB << 154 MB;
// attn fully overwrites d_out afterwards, all stream-ordered).
// ---------------------------------------------------------------------------
extern "C" void kernel_launch(void* const* d_in, const int* in_sizes, int n_in,
                              void* d_out, int out_size, void* d_ws, size_t ws_size,
                              hipStream_t stream) {
    const float* x  = (const float*)d_in[0];
    const float* z  = (const float*)d_in[1];
    const float* Wk = (const float*)d_in[2];
    const float* bk = (const float*)d_in[3];
    const float* Wv = (const float*)d_in[4];
    const float* bv = (const float*)d_in[5];
    float* out  = (float*)d_out;
    float* part = (float*)d_out;   // scratch: KCHUNKS*ROWS*48*4 = 38.5 MB
    float* kv   = (float*)d_ws;    // 2*25088*24*4 = 4.8 MB

    proj_kernel<<<(ROWS / 128) * KCHUNKS, 256, 0, stream>>>(z, Wk, Wv, part);
    reduce_kernel<<<(ROWS * PCOLS) / 256, 256, 0, stream>>>(part, bk, bv, kv);
    attn_kernel<<<B_ * QBLK, 256, 0, stream>>>(x, kv, out);
}

// Round 5
// 428.000 us; speedup vs baseline: 1.2051x; 1.0416x over previous
//
#include <hip/hip_runtime.h>
#include <math.h>

// Problem constants
#define B_   512
#define C_   24      // head dim of q / output channels
#define HW_  3136    // 56*56 queries per batch
#define M_   49      // kv tokens
#define D_   768     // z feature dim
#define DK_  24      // k/v head dim
#define ROWS (B_*M_)       // 25088 rows of z (b*49+m)
#define VOFF (ROWS*DK_)    // float offset of v block in kv workspace

#define KCHUNKS 8
#define KCH     (D_/KCHUNKS)   // 96
#define QBLK    13             // ceil(3136/256) query blocks per batch
#define PCOLS   48
#define PSTRIDE ((size_t)ROWS * PCOLS)   // floats per chunk-partial (1,204,224)
#define KVROW   (M_*DK_)       // 1176 floats per batch per k (or v)

// ---------------------------------------------------------------------------
// Kernel 1: k/v projection, split-K=8, atomic-free.  256 thr, 128-row tiles.
// ROUND-4 CHANGE: W-staging index remap so consecutive threads read
//   consecutive addresses (c fastest, was d fastest = 96B stride,
//   1-float-per-cacheline).  Now 96B-contiguous runs per wave.
// ---------------------------------------------------------------------------
__global__ __launch_bounds__(256, 4) void proj_kernel(
    const float* __restrict__ z, const float* __restrict__ Wk,
    const float* __restrict__ Wv, float* __restrict__ part)
{
    __shared__ float zt[128][36];  // stride 36 floats (16B-aligned rows)
    __shared__ float wt[48][36];   // wt[c][kk]  (transposed W chunk)

    const int t     = threadIdx.x;
    const int tile  = blockIdx.x >> 3;          // 196 row tiles
    const int chunk = blockIdx.x & 7;           // 8 K-chunks of 96
    const int r0    = tile * 128;
    const int rb    = t & 31;                   // rows rb + {0,32,64,96}
    const int c0    = (t >> 5) * 6;             // cols c0..c0+5, never straddles 24

    float acc[4][6];
    #pragma unroll
    for (int i = 0; i < 4; ++i)
        #pragma unroll
        for (int j = 0; j < 6; ++j) acc[i][j] = 0.f;

    for (int s = 0; s < KCH; s += 32) {
        const int kc = chunk * KCH + s;
        // stage z tile 128x32 (float4/thread x4, coalesced 128B segments)
        #pragma unroll
        for (int p = 0; p < 4; ++p) {
            int lin = p * 256 + t;              // 0..1023
            int row = lin >> 3;
            int col = (lin & 7) * 4;
            const float4 zv = *(const float4*)(z + (size_t)(r0 + row) * D_ + kc + col);
            *(float4*)&zt[row][col] = zv;
        }
        // stage W chunk 32x48 transposed into wt[c][d]; c fastest -> coalesced
        #pragma unroll
        for (int i = 0; i < 6; ++i) {
            int idx = i * 256 + t;              // 0..1535
            int c = idx % 48;
            int d = idx / 48;                   // 0..31
            wt[c][d] = (c < 24) ? Wk[(kc + d) * DK_ + c] : Wv[(kc + d) * DK_ + (c - 24)];
        }
        __syncthreads();
        #pragma unroll
        for (int k4 = 0; k4 < 8; ++k4) {
            float4 za[4], wa[6];
            #pragma unroll
            for (int i = 0; i < 4; ++i) za[i] = *(const float4*)&zt[rb + 32 * i][k4 * 4];
            #pragma unroll
            for (int j = 0; j < 6; ++j) wa[j] = *(const float4*)&wt[c0 + j][k4 * 4];
            #pragma unroll
            for (int i = 0; i < 4; ++i)
                #pragma unroll
                for (int j = 0; j < 6; ++j) {
                    acc[i][j] += za[i].x * wa[j].x;
                    acc[i][j] += za[i].y * wa[j].y;
                    acc[i][j] += za[i].z * wa[j].z;
                    acc[i][j] += za[i].w * wa[j].w;
                }
        }
        __syncthreads();
    }

    // epilogue: plain partial stores (float2: c0 even -> 8B aligned)
    #pragma unroll
    for (int i = 0; i < 4; ++i) {
        float* base = part + (size_t)chunk * PSTRIDE
                           + (size_t)(r0 + rb + 32 * i) * PCOLS + c0;
        #pragma unroll
        for (int j = 0; j < 6; j += 2) {
            float2 v2 = make_float2(acc[i][j], acc[i][j + 1]);
            *(float2*)(base + j) = v2;
        }
    }
}

// ---------------------------------------------------------------------------
// Kernel 1b: reduce partials + biases into kv.  ~8 us HBM-bound.
// ---------------------------------------------------------------------------
__global__ __launch_bounds__(256) void reduce_kernel(
    const float* __restrict__ part, const float* __restrict__ bk,
    const float* __restrict__ bv, float* __restrict__ kv)
{
    int i = blockIdx.x * 256 + threadIdx.x;     // i in [0, ROWS*48)
    int row = i / PCOLS;
    int c   = i - row * PCOLS;

    float v = 0.f;
    #pragma unroll
    for (int k = 0; k < KCHUNKS; ++k) v += part[(size_t)k * PSTRIDE + i];

    if (c < DK_) kv[(size_t)row * DK_ + c]               = v + bk[c];
    else         kv[VOFF + (size_t)row * DK_ + (c - DK_)] = v + bv[c - DK_];
}

// ---------------------------------------------------------------------------
// Kernel 2: attention + residual.  One thread per query, streaming max-free
// softmax (dots std ~0.58, fp32-safe).
//
// ROUND-4 CHANGE (latency theory):
//   Round-3 result: VALU-issue time collapsed to 67us (~floor) but dur rose
//   to 155us at VALUBusy 43% -> latency-bound on the per-m serial chain
//   (12 uniform s_loads @ ~200cy L2 latency, unroll-1 blocks prefetch).
//   Fix: stage the batch's k/v slab (9408 B) in LDS once per block;
//   hot loop reads rows as broadcast ds_read_b128 (uniform addr =
//   conflict-free, short latency); #pragma unroll 2 lets next-iter ds_reads
//   hide under current FMAs.  All threads stay alive through staging.
// ---------------------------------------------------------------------------
__global__ __launch_bounds__(256, 4) void attn_kernel(
    const float* __restrict__ x, const float* __restrict__ kv, float* __restrict__ out)
{
    __shared__ float kvs[2 * KVROW];   // k rows [49][24] then v rows [49][24]

    const int b  = blockIdx.x / QBLK;
    const int hw = (blockIdx.x % QBLK) * 256 + threadIdx.x;
    const int t  = threadIdx.x;

    // cooperative stage: 294 float4 of k, 294 float4 of v (both 16B-aligned)
    {
        const float4* ksrc = (const float4*)(kv + (size_t)b * KVROW);
        const float4* vsrc = (const float4*)(kv + VOFF + (size_t)b * KVROW);
        float4* dst = (float4*)kvs;
        for (int s = t; s < KVROW / 4; s += 256) dst[s]             = ksrc[s];
        for (int s = t; s < KVROW / 4; s += 256) dst[s + KVROW / 4] = vsrc[s];
    }
    __syncthreads();

    if (hw < HW_) {
        const float scale = 0.20412414523193154f;               // 24^-0.5

        const float* xb = x + (size_t)b * (C_ * HW_);
        float q[C_];
        #pragma unroll
        for (int c = 0; c < C_; ++c) q[c] = xb[c * HW_ + hw] * scale;   // coalesced

        float o[C_];
        #pragma unroll
        for (int c = 0; c < C_; ++c) o[c] = 0.f;
        float s = 0.f;

        const float* ks = kvs;            // [49][24]
        const float* vs = kvs + KVROW;    // [49][24]

        #pragma unroll 2
        for (int m = 0; m < M_; ++m) {
            const float4* kr = (const float4*)(ks + m * DK_);   // broadcast b128
            float a0 = 0.f, a1 = 0.f, a2 = 0.f, a3 = 0.f;
            #pragma unroll
            for (int c4 = 0; c4 < 6; ++c4) {
                float4 kf = kr[c4];
                a0 += q[c4 * 4 + 0] * kf.x;
                a1 += q[c4 * 4 + 1] * kf.y;
                a2 += q[c4 * 4 + 2] * kf.z;
                a3 += q[c4 * 4 + 3] * kf.w;
            }
            float p = __expf((a0 + a1) + (a2 + a3));
            s += p;
            const float4* vr = (const float4*)(vs + m * DK_);
            #pragma unroll
            for (int c4 = 0; c4 < 6; ++c4) {
                float4 vf = vr[c4];
                o[c4 * 4 + 0] += p * vf.x;
                o[c4 * 4 + 1] += p * vf.y;
                o[c4 * 4 + 2] += p * vf.z;
                o[c4 * 4 + 3] += p * vf.w;
            }
        }
        const float inv = 1.f / s;

        // flat-view residual: thread q owns flat [q*24, q*24+24)
        const float* xr = xb + (size_t)hw * C_;
        float*       ob = out + (size_t)b * (C_ * HW_) + (size_t)hw * C_;
        #pragma unroll
        for (int c4 = 0; c4 < C_; c4 += 4) {
            float4 xv = *(const float4*)(xr + c4);
            float4 ov;
            ov.x = xv.x + o[c4+0] * inv;
            ov.y = xv.y + o[c4+1] * inv;
            ov.z = xv.z + o[c4+2] * inv;
            ov.w = xv.w + o[c4+3] * inv;
            *(float4*)(ob + c4) = ov;
        }
    }
}

// ---------------------------------------------------------------------------
// Launch: proj partials land in d_out used as scratch (38.5 MB << 154 MB;
// attn fully overwrites d_out afterwards, all stream-ordered).
// ---------------------------------------------------------------------------
extern "C" void kernel_launch(void* const* d_in, const int* in_sizes, int n_in,
                              void* d_out, int out_size, void* d_ws, size_t ws_size,
                              hipStream_t stream) {
    const float* x  = (const float*)d_in[0];
    const float* z  = (const float*)d_in[1];
    const float* Wk = (const float*)d_in[2];
    const float* bk = (const float*)d_in[3];
    const float* Wv = (const float*)d_in[4];
    const float* bv = (const float*)d_in[5];
    float* out  = (float*)d_out;
    float* part = (float*)d_out;   // scratch: KCHUNKS*ROWS*48*4 = 38.5 MB
    float* kv   = (float*)d_ws;    // 2*25088*24*4 = 4.8 MB

    proj_kernel<<<(ROWS / 128) * KCHUNKS, 256, 0, stream>>>(z, Wk, Wv, part);
    reduce_kernel<<<(ROWS * PCOLS) / 256, 256, 0, stream>>>(part, bk, bv, kv);
    attn_kernel<<<B_ * QBLK, 256, 0, stream>>>(x, kv, out);
}